// Round 1
// baseline (528.223 us; speedup 1.0000x reference)
//
#include <hip/hip_runtime.h>
#include <hip/hip_bf16.h>

typedef __attribute__((ext_vector_type(8))) short bf16x8;
typedef __attribute__((ext_vector_type(4))) float f32x4;

#define GLOAD_LDS16(gptr, lptr) \
  __builtin_amdgcn_global_load_lds((const __attribute__((address_space(1))) void*)(gptr), \
                                   (__attribute__((address_space(3))) void*)(lptr), 16, 0, 0)

__device__ __forceinline__ unsigned short f2b(float f) {
  union { float f; unsigned u; } x; x.f = f;
  unsigned r = x.u + 0x7fffu + ((x.u >> 16) & 1u);
  return (unsigned short)(r >> 16);
}
__device__ __forceinline__ float b2f(unsigned short u) {
  union { unsigned u; float f; } x; x.u = ((unsigned)u) << 16;
  return x.f;
}

// ---------------- fp32 -> bf16 cast ----------------
__global__ void cast_kernel(const float* __restrict__ in, unsigned short* __restrict__ out, int n) {
  const int i = (blockIdx.x * 256 + threadIdx.x) * 4;
  if (i < n) {
    const float4 v = *(const float4*)(in + i);
    ushort4 r;
    r.x = f2b(v.x); r.y = f2b(v.y); r.z = f2b(v.z); r.w = f2b(v.w);
    *(ushort4*)(out + i) = r;
  }
}

// ---------------- GEMM: C[M][N] = A[M][K] * Bm[N][K]^T + bias ----------------
// 128x128 tile, 4 waves (2x2 of 64x64), BK=32, global_load_lds staging.
template<int OUTF32>
__global__ __launch_bounds__(256)
void gemm_bt(const unsigned short* __restrict__ A,
             const unsigned short* __restrict__ Bm,
             const float* __restrict__ bias,
             void* __restrict__ Cp,
             int M, int N, int K)
{
  __shared__ __align__(16) unsigned short As[128 * 32];
  __shared__ __align__(16) unsigned short Bs[128 * 32];
  const int t  = threadIdx.x;
  const int l  = t & 63;
  const int w  = t >> 6;
  const int lr = l & 15;
  const int lk = (l >> 4) << 3;
  const int wr = (w >> 1) << 6;   // wave row offset in tile
  const int wc = (w & 1) << 6;    // wave col offset
  const int bm = blockIdx.y, bn = blockIdx.x;

  f32x4 acc[4][4] = {};

  const int srow = t >> 2;            // 0..63
  const int scol = (t & 3) << 3;      // bf16 col offset
  const unsigned short* Ag = A  + (long)(bm * 128 + srow) * K + scol;
  const unsigned short* Bg = Bm + (long)(bn * 128 + srow) * K + scol;
  unsigned short* AsP = &As[srow * 32 + scol];
  unsigned short* BsP = &Bs[srow * 32 + scol];
  const long rstep = (long)64 * K;

  for (int k0 = 0; k0 < K; k0 += 32) {
    GLOAD_LDS16(Ag + k0,         AsP);
    GLOAD_LDS16(Ag + rstep + k0, AsP + 64 * 32);
    GLOAD_LDS16(Bg + k0,         BsP);
    GLOAD_LDS16(Bg + rstep + k0, BsP + 64 * 32);
    __syncthreads();
    bf16x8 af[4], bfr[4];
#pragma unroll
    for (int i = 0; i < 4; ++i) af[i]  = *(const bf16x8*)&As[(wr + i * 16 + lr) * 32 + lk];
#pragma unroll
    for (int i = 0; i < 4; ++i) bfr[i] = *(const bf16x8*)&Bs[(wc + i * 16 + lr) * 32 + lk];
#pragma unroll
    for (int i = 0; i < 4; ++i)
#pragma unroll
      for (int j = 0; j < 4; ++j)
        acc[i][j] = __builtin_amdgcn_mfma_f32_16x16x32_bf16(af[i], bfr[j], acc[i][j], 0, 0, 0);
    __syncthreads();
  }

  // C/D layout: col = lane&15, row = (lane>>4)*4 + reg  [measured m89]
  const int row0 = bm * 128 + wr + ((l >> 4) << 2);
  const int col0 = bn * 128 + wc + lr;
#pragma unroll
  for (int j = 0; j < 4; ++j) {
    const int col = col0 + j * 16;
    const float bv = bias ? bias[col] : 0.0f;
#pragma unroll
    for (int i = 0; i < 4; ++i) {
#pragma unroll
      for (int r = 0; r < 4; ++r) {
        const int row = row0 + i * 16 + r;
        const float v = acc[i][j][r] + bv;
        if (OUTF32) ((float*)Cp)[(long)row * N + col] = v;
        else ((unsigned short*)Cp)[(long)row * N + col] = f2b(v);
      }
    }
  }
}

// ---------------- RoPE: qkv[B][T][3][H*128] -> Qr,Kr (B,H,T,D) bf16 ----------------
__global__ void rope_kernel(const unsigned short* __restrict__ qkv,
                            unsigned short* __restrict__ Qr,
                            unsigned short* __restrict__ Kr)
{
  const int T = 2048;
  const int idx = blockIdx.x * 256 + threadIdx.x;   // [bh(5) | t(11) | d(6)]
  const int d  = idx & 63;
  const int tt = (idx >> 6) & (T - 1);
  const int bh = idx >> 17;
  const int b = bh >> 4, h = bh & 15;
  const long base = ((long)(b * T + tt) * 3) * 2048 + h * 128;
  // inv_freq = 10000^(-d/64) = 2^(-d * log2(10000)/64)
  const float inv = exp2f(-(float)d * 0.2076205059304602f);
  const float fr = (float)tt * inv;
  float sn, cs;
  sincosf(fr, &sn, &cs);
  const float q1 = b2f(qkv[base + 2 * d]);
  const float q2 = b2f(qkv[base + 2 * d + 1]);
  const float k1 = b2f(qkv[base + 2048 + 2 * d]);
  const float k2 = b2f(qkv[base + 2048 + 2 * d + 1]);
  const long ob = ((long)bh * T + tt) * 128;
  Qr[ob + d]      = f2b(q1 * cs - q2 * sn);
  Qr[ob + 64 + d] = f2b(q1 * sn + q2 * cs);
  Kr[ob + d]      = f2b(k1 * cs - k2 * sn);
  Kr[ob + 64 + d] = f2b(k1 * sn + k2 * cs);
}

// ---------------- V transpose: qkv(...,s=2,...) -> Vt (B,H,D,T) bf16 ----------------
__global__ void vtrans_kernel(const unsigned short* __restrict__ qkv,
                              unsigned short* __restrict__ Vt)
{
  const int T = 2048;
  __shared__ unsigned short ld[128][65];
  const int bh = blockIdx.y, tt = blockIdx.x;
  const int b = bh >> 4, h = bh & 15;
  const int t = threadIdx.x;
#pragma unroll
  for (int i = 0; i < 32; ++i) {
    const int idx = i * 256 + t;
    const int d = idx & 127, tr = idx >> 7;
    ld[d][tr] = qkv[((long)(b * T + tt * 64 + tr) * 3 + 2) * 2048 + h * 128 + d];
  }
  __syncthreads();
#pragma unroll
  for (int i = 0; i < 32; ++i) {
    const int idx = i * 256 + t;
    const int tc = idx & 63, dr = idx >> 6;
    Vt[((long)bh * 128 + dr) * T + tt * 64 + tc] = ld[dr][tc];
  }
}

// ---------------- causal flash attention ----------------
// grid (T/64, B*H); 4 waves x 16 q-rows; KV tile = 64.
__global__ __launch_bounds__(256)
void attn_fwd(const unsigned short* __restrict__ Q,
              const unsigned short* __restrict__ Kg,
              const unsigned short* __restrict__ Vt,
              unsigned short* __restrict__ O, int T)
{
  __shared__ __align__(16) unsigned short Ks[64 * 128];   // [kv][d]
  __shared__ __align__(16) unsigned short Vs[128 * 64];   // [d][kv]
  __shared__ __align__(16) unsigned short Ps[4][16 * 64]; // per-wave P
  const int t = threadIdx.x;
  const int w = t >> 6, l = t & 63;
  const int lr = l & 15, lk = (l >> 4) << 3;
  const int bh = blockIdx.y, qt = blockIdx.x;
  const int q0 = qt * 64 + w * 16;
  const long hbase = (long)bh * T * 128;
  const int roff = (l >> 4) << 2;

  bf16x8 qf[4];
  const unsigned short* Qrow = Q + hbase + (long)(q0 + lr) * 128;
#pragma unroll
  for (int ds = 0; ds < 4; ++ds) qf[ds] = *(const bf16x8*)&Qrow[ds * 32 + lk];

  f32x4 o[8] = {};
  float m[4]    = {-INFINITY, -INFINITY, -INFINITY, -INFINITY};
  float lsum[4] = {0.f, 0.f, 0.f, 0.f};

  const int ntile = qt + 1;
  for (int kt = 0; kt < ntile; ++kt) {
#pragma unroll
    for (int c = 0; c < 4; ++c) {
      const int o2 = t * 16 + c * 4096;
      const int krow = o2 >> 8, kcolb = o2 & 255;
      GLOAD_LDS16((const char*)Kg + (hbase + (long)(kt * 64 + krow) * 128) * 2 + kcolb,
                  (char*)Ks + o2);
      const int vrow = o2 >> 7, vcolb = o2 & 127;
      GLOAD_LDS16((const char*)Vt + (((long)bh * 128 + vrow) * T + kt * 64) * 2 + vcolb,
                  (char*)Vs + o2);
    }
    __syncthreads();

    // S = Q K^T
    f32x4 s[4] = {};
#pragma unroll
    for (int tj = 0; tj < 4; ++tj)
#pragma unroll
      for (int ds = 0; ds < 4; ++ds) {
        bf16x8 kf = *(const bf16x8*)&Ks[(tj * 16 + lr) * 128 + ds * 32 + lk];
        s[tj] = __builtin_amdgcn_mfma_f32_16x16x32_bf16(qf[ds], kf, s[tj], 0, 0, 0);
      }
    const float scale = 0.08838834764831845f; // 1/sqrt(128)
#pragma unroll
    for (int tj = 0; tj < 4; ++tj) s[tj] *= scale;
    if (kt == qt) {
#pragma unroll
      for (int tj = 0; tj < 4; ++tj)
#pragma unroll
        for (int j = 0; j < 4; ++j)
          if (kt * 64 + tj * 16 + lr > q0 + roff + j) s[tj][j] = -INFINITY;
    }

    // online softmax (rows live in 16-lane groups)
    float corr[4];
#pragma unroll
    for (int j = 0; j < 4; ++j) {
      float v = fmaxf(fmaxf(s[0][j], s[1][j]), fmaxf(s[2][j], s[3][j]));
      v = fmaxf(v, __shfl_xor(v, 1, 64));
      v = fmaxf(v, __shfl_xor(v, 2, 64));
      v = fmaxf(v, __shfl_xor(v, 4, 64));
      v = fmaxf(v, __shfl_xor(v, 8, 64));
      const float mn = fmaxf(m[j], v);
      corr[j] = __expf(m[j] - mn);
      m[j] = mn;
    }
    float rs[4] = {0.f, 0.f, 0.f, 0.f};
#pragma unroll
    for (int tj = 0; tj < 4; ++tj)
#pragma unroll
      for (int j = 0; j < 4; ++j) {
        const float p = __expf(s[tj][j] - m[j]);
        rs[j] += p;
        Ps[w][(roff + j) * 64 + tj * 16 + lr] = f2b(p);
      }
#pragma unroll
    for (int j = 0; j < 4; ++j) {
      float v = rs[j];
      v += __shfl_xor(v, 1, 64);
      v += __shfl_xor(v, 2, 64);
      v += __shfl_xor(v, 4, 64);
      v += __shfl_xor(v, 8, 64);
      lsum[j] = lsum[j] * corr[j] + v;
    }
#pragma unroll
    for (int nj = 0; nj < 8; ++nj)
#pragma unroll
      for (int j = 0; j < 4; ++j) o[nj][j] *= corr[j];

    // O += P V  (P from per-wave LDS in A-fragment layout; V from Vs[d][kv])
#pragma unroll
    for (int ks = 0; ks < 2; ++ks) {
      bf16x8 pf = *(const bf16x8*)&Ps[w][lr * 64 + ks * 32 + lk];
#pragma unroll
      for (int nj = 0; nj < 8; ++nj) {
        bf16x8 vf = *(const bf16x8*)&Vs[(nj * 16 + lr) * 64 + ks * 32 + lk];
        o[nj] = __builtin_amdgcn_mfma_f32_16x16x32_bf16(pf, vf, o[nj], 0, 0, 0);
      }
    }
    __syncthreads();
  }

  float inv[4];
#pragma unroll
  for (int j = 0; j < 4; ++j) inv[j] = 1.0f / lsum[j];
  const int b = bh >> 4, h = bh & 15;
#pragma unroll
  for (int nj = 0; nj < 8; ++nj)
#pragma unroll
    for (int j = 0; j < 4; ++j) {
      const int q = q0 + roff + j;
      const int d = nj * 16 + lr;
      O[(long)(b * T + q) * 2048 + h * 128 + d] = f2b(o[nj][j] * inv[j]);
    }
}

// ---------------- launch ----------------
extern "C" void kernel_launch(void* const* d_in, const int* in_sizes, int n_in,
                              void* d_out, int out_size, void* d_ws, size_t ws_size,
                              hipStream_t stream)
{
  const int B = 2, T = 2048, C = 2048;
  const int M = B * T;        // 4096
  const int N1 = 3 * C;       // 6144
  const float* x    = (const float*)d_in[0];
  const float* Wqkv = (const float*)d_in[1];
  const float* bqkv = (const float*)d_in[2];
  const float* Wout = (const float*)d_in[3];
  const float* bout = (const float*)d_in[4];
  float* out = (float*)d_out;

  char* p = (char*)d_ws;
  unsigned short* xb    = (unsigned short*)p; p += (size_t)M * C * 2;    // 16 MB
  unsigned short* wqkvb = (unsigned short*)p; p += (size_t)N1 * C * 2;   // 24 MB
  unsigned short* woutb = (unsigned short*)p; p += (size_t)C * C * 2;    // 8 MB
  unsigned short* qkv   = (unsigned short*)p; p += (size_t)M * N1 * 2;   // 48 MB
  unsigned short* Qr    = (unsigned short*)p; p += (size_t)M * C * 2;    // 16 MB
  unsigned short* Kr    = (unsigned short*)p; p += (size_t)M * C * 2;    // 16 MB
  unsigned short* Vt    = (unsigned short*)p; p += (size_t)M * C * 2;    // 16 MB
  unsigned short* Ob    = xb;  // xb dead after QKV GEMM — reuse for attention output

  cast_kernel<<<M * C / 1024, 256, 0, stream>>>(x, xb, M * C);
  cast_kernel<<<N1 * C / 1024, 256, 0, stream>>>(Wqkv, wqkvb, N1 * C);
  cast_kernel<<<C * C / 1024, 256, 0, stream>>>(Wout, woutb, C * C);

  gemm_bt<0><<<dim3(N1 / 128, M / 128), 256, 0, stream>>>(xb, wqkvb, bqkv, qkv, M, N1, C);

  rope_kernel<<<(32 * T * 64) / 256, 256, 0, stream>>>(qkv, Qr, Kr);
  vtrans_kernel<<<dim3(T / 64, 32), 256, 0, stream>>>(qkv, Vt);

  attn_fwd<<<dim3(T / 64, 32), 256, 0, stream>>>(Qr, Kr, Vt, Ob, T);

  gemm_bt<1><<<dim3(C / 128, M / 128), 256, 0, stream>>>(Ob, woutb, bout, out, M, C, C);
}

// Round 2
// 336.412 us; speedup vs baseline: 1.5702x; 1.5702x over previous
//
#include <hip/hip_runtime.h>
#include <hip/hip_bf16.h>

typedef __attribute__((ext_vector_type(8))) short bf16x8;
typedef __attribute__((ext_vector_type(4))) float f32x4;

#define GLOAD_LDS16(gptr, lptr) \
  __builtin_amdgcn_global_load_lds((const __attribute__((address_space(1))) void*)(gptr), \
                                   (__attribute__((address_space(3))) void*)(lptr), 16, 0, 0)

__device__ __forceinline__ unsigned short f2b(float f) {
  union { float f; unsigned u; } x; x.f = f;
  unsigned r = x.u + 0x7fffu + ((x.u >> 16) & 1u);
  return (unsigned short)(r >> 16);
}
__device__ __forceinline__ float b2f(unsigned short u) {
  union { unsigned u; float f; } x; x.u = ((unsigned)u) << 16;
  return x.f;
}

// ---------------- fp32 -> bf16 cast ----------------
__global__ void cast_kernel(const float* __restrict__ in, unsigned short* __restrict__ out, int n) {
  const int i = (blockIdx.x * 256 + threadIdx.x) * 4;
  if (i < n) {
    const float4 v = *(const float4*)(in + i);
    ushort4 r;
    r.x = f2b(v.x); r.y = f2b(v.y); r.z = f2b(v.z); r.w = f2b(v.w);
    *(ushort4*)(out + i) = r;
  }
}

// ---------------- GEMM: C[M][N] = A[M][K] * Bm[N][K]^T + bias ----------------
// 128x128 tile, 4 waves (2x2 of 64x64), BK=32, global_load_lds staging.
template<int OUTF32>
__global__ __launch_bounds__(256)
void gemm_bt(const unsigned short* __restrict__ A,
             const unsigned short* __restrict__ Bm,
             const float* __restrict__ bias,
             void* __restrict__ Cp,
             int M, int N, int K)
{
  __shared__ __align__(16) unsigned short As[128 * 32];
  __shared__ __align__(16) unsigned short Bs[128 * 32];
  const int t  = threadIdx.x;
  const int l  = t & 63;
  const int w  = t >> 6;
  const int lr = l & 15;
  const int lk = (l >> 4) << 3;
  const int wr = (w >> 1) << 6;   // wave row offset in tile
  const int wc = (w & 1) << 6;    // wave col offset
  const int bm = blockIdx.y, bn = blockIdx.x;

  f32x4 acc[4][4] = {};

  const int srow = t >> 2;            // 0..63
  const int scol = (t & 3) << 3;      // bf16 col offset
  const unsigned short* Ag = A  + (long)(bm * 128 + srow) * K + scol;
  const unsigned short* Bg = Bm + (long)(bn * 128 + srow) * K + scol;
  unsigned short* AsP = &As[srow * 32 + scol];
  unsigned short* BsP = &Bs[srow * 32 + scol];
  const long rstep = (long)64 * K;

  for (int k0 = 0; k0 < K; k0 += 32) {
    GLOAD_LDS16(Ag + k0,         AsP);
    GLOAD_LDS16(Ag + rstep + k0, AsP + 64 * 32);
    GLOAD_LDS16(Bg + k0,         BsP);
    GLOAD_LDS16(Bg + rstep + k0, BsP + 64 * 32);
    __syncthreads();
    bf16x8 af[4], bfr[4];
#pragma unroll
    for (int i = 0; i < 4; ++i) af[i]  = *(const bf16x8*)&As[(wr + i * 16 + lr) * 32 + lk];
#pragma unroll
    for (int i = 0; i < 4; ++i) bfr[i] = *(const bf16x8*)&Bs[(wc + i * 16 + lr) * 32 + lk];
#pragma unroll
    for (int i = 0; i < 4; ++i)
#pragma unroll
      for (int j = 0; j < 4; ++j)
        acc[i][j] = __builtin_amdgcn_mfma_f32_16x16x32_bf16(af[i], bfr[j], acc[i][j], 0, 0, 0);
    __syncthreads();
  }

  // C/D layout: col = lane&15, row = (lane>>4)*4 + reg  [measured m89]
  const int row0 = bm * 128 + wr + ((l >> 4) << 2);
  const int col0 = bn * 128 + wc + lr;
#pragma unroll
  for (int j = 0; j < 4; ++j) {
    const int col = col0 + j * 16;
    const float bv = bias ? bias[col] : 0.0f;
#pragma unroll
    for (int i = 0; i < 4; ++i) {
#pragma unroll
      for (int r = 0; r < 4; ++r) {
        const int row = row0 + i * 16 + r;
        const float v = acc[i][j][r] + bv;
        if (OUTF32) ((float*)Cp)[(long)row * N + col] = v;
        else ((unsigned short*)Cp)[(long)row * N + col] = f2b(v);
      }
    }
  }
}

// ---------------- RoPE: qkv[B][T][3][H*128] -> Qr,Kr (B,H,T,D) bf16 ----------------
__global__ void rope_kernel(const unsigned short* __restrict__ qkv,
                            unsigned short* __restrict__ Qr,
                            unsigned short* __restrict__ Kr)
{
  const int T = 2048;
  const int idx = blockIdx.x * 256 + threadIdx.x;   // [bh(5) | t(11) | d(6)]
  const int d  = idx & 63;
  const int tt = (idx >> 6) & (T - 1);
  const int bh = idx >> 17;
  const int b = bh >> 4, h = bh & 15;
  const long base = ((long)(b * T + tt) * 3) * 2048 + h * 128;
  // inv_freq = 10000^(-d/64) = 2^(-d * log2(10000)/64)
  const float inv = exp2f(-(float)d * 0.2076205059304602f);
  const float fr = (float)tt * inv;
  float sn, cs;
  sincosf(fr, &sn, &cs);
  const float q1 = b2f(qkv[base + 2 * d]);
  const float q2 = b2f(qkv[base + 2 * d + 1]);
  const float k1 = b2f(qkv[base + 2048 + 2 * d]);
  const float k2 = b2f(qkv[base + 2048 + 2 * d + 1]);
  const long ob = ((long)bh * T + tt) * 128;
  Qr[ob + d]      = f2b(q1 * cs - q2 * sn);
  Qr[ob + 64 + d] = f2b(q1 * sn + q2 * cs);
  Kr[ob + d]      = f2b(k1 * cs - k2 * sn);
  Kr[ob + 64 + d] = f2b(k1 * sn + k2 * cs);
}

// ---------------- V transpose: qkv(...,s=2,...) -> Vt (B,H,D,T) bf16 ----------------
__global__ void vtrans_kernel(const unsigned short* __restrict__ qkv,
                              unsigned short* __restrict__ Vt)
{
  const int T = 2048;
  __shared__ unsigned short ld[128][65];
  const int bh = blockIdx.y, tt = blockIdx.x;
  const int b = bh >> 4, h = bh & 15;
  const int t = threadIdx.x;
#pragma unroll
  for (int i = 0; i < 32; ++i) {
    const int idx = i * 256 + t;
    const int d = idx & 127, tr = idx >> 7;
    ld[d][tr] = qkv[((long)(b * T + tt * 64 + tr) * 3 + 2) * 2048 + h * 128 + d];
  }
  __syncthreads();
#pragma unroll
  for (int i = 0; i < 32; ++i) {
    const int idx = i * 256 + t;
    const int tc = idx & 63, dr = idx >> 6;
    Vt[((long)bh * 128 + dr) * T + tt * 64 + tc] = ld[dr][tc];
  }
}

// ---------------- causal flash attention ----------------
// grid (B*H, T/64), qt reversed (heavy first); 4 waves x 16 q-rows; KV tile = 64.
// K/V double-buffered + prefetch; XOR-swizzled LDS (both-sides via pre-swizzled src).
__global__ __launch_bounds__(256)
void attn_fwd(const unsigned short* __restrict__ Q,
              const unsigned short* __restrict__ Kg,
              const unsigned short* __restrict__ Vt,
              unsigned short* __restrict__ O, int T)
{
  __shared__ __align__(16) unsigned short Ks[2][64 * 128];   // [kv][d], swizzled
  __shared__ __align__(16) unsigned short Vs[2][128 * 64];   // [d][kv], swizzled
  __shared__ __align__(16) unsigned short Ps[4][16 * 64];    // per-wave P, swizzled
  const int t = threadIdx.x;
  const int w = t >> 6, l = t & 63;
  const int lr = l & 15;
  const int g16 = (l >> 4) << 4;       // byte offset of lane's k-group (16B)
  const int sw = (lr & 7) << 4;        // read-side XOR swizzle
  const int bh = blockIdx.x;
  const int qt = (gridDim.y - 1) - blockIdx.y;   // heavy blocks dispatch first
  const int q0 = qt * 64 + w * 16;
  const long hbase = (long)bh * T * 128;         // elements
  const long hbase2 = hbase * 2;                 // bytes
  const long T2 = (long)T * 2;
  const int roff = (l >> 4) << 2;

  bf16x8 qf[4];
  const unsigned short* Qrow = Q + hbase + (long)(q0 + lr) * 128;
#pragma unroll
  for (int ds = 0; ds < 4; ++ds) qf[ds] = *(const bf16x8*)&Qrow[ds * 32 + (g16 >> 1)];

  f32x4 o[8] = {};
  float m[4]    = {-INFINITY, -INFINITY, -INFINITY, -INFINITY};
  float lsum[4] = {0.f, 0.f, 0.f, 0.f};

  // stage tile kt into buffer buf, with pre-swizzled global source
  auto stage = [&](int kt, int buf) {
#pragma unroll
    for (int c = 0; c < 4; ++c) {
      const int o2 = t * 16 + c * 4096;
      const int krow = o2 >> 8, kcb = o2 & 255;
      GLOAD_LDS16((const char*)Kg + hbase2 + (long)kt * 16384 + krow * 256 + (kcb ^ ((krow & 7) << 4)),
                  (char*)Ks[buf] + o2);
      const int vrow = o2 >> 7, vcb = o2 & 127;
      GLOAD_LDS16((const char*)Vt + (long)(bh * 128 + vrow) * T2 + (long)kt * 128 + (vcb ^ ((vrow & 7) << 4)),
                  (char*)Vs[buf] + o2);
    }
  };

  const int ntile = qt + 1;
  stage(0, 0);
  __syncthreads();

  for (int kt = 0; kt < ntile; ++kt) {
    const int cur = kt & 1;
    if (kt + 1 < ntile) stage(kt + 1, cur ^ 1);

    const char* KsB = (const char*)Ks[cur];
    const char* VsB = (const char*)Vs[cur];

    // S = Q K^T
    f32x4 s[4] = {};
    __builtin_amdgcn_s_setprio(1);
#pragma unroll
    for (int tj = 0; tj < 4; ++tj)
#pragma unroll
      for (int ds = 0; ds < 4; ++ds) {
        bf16x8 kf = *(const bf16x8*)(KsB + (tj * 16 + lr) * 256 + ((ds * 64 + g16) ^ sw));
        s[tj] = __builtin_amdgcn_mfma_f32_16x16x32_bf16(qf[ds], kf, s[tj], 0, 0, 0);
      }
    __builtin_amdgcn_s_setprio(0);

    const float scale = 0.08838834764831845f; // 1/sqrt(128)
#pragma unroll
    for (int tj = 0; tj < 4; ++tj) s[tj] *= scale;
    if (kt == qt) {
#pragma unroll
      for (int tj = 0; tj < 4; ++tj)
#pragma unroll
        for (int j = 0; j < 4; ++j)
          if (kt * 64 + tj * 16 + lr > q0 + roff + j) s[tj][j] = -INFINITY;
    }

    // online softmax (rows live in 16-lane groups)
    float corr[4];
#pragma unroll
    for (int j = 0; j < 4; ++j) {
      float v = fmaxf(fmaxf(s[0][j], s[1][j]), fmaxf(s[2][j], s[3][j]));
      v = fmaxf(v, __shfl_xor(v, 1, 64));
      v = fmaxf(v, __shfl_xor(v, 2, 64));
      v = fmaxf(v, __shfl_xor(v, 4, 64));
      v = fmaxf(v, __shfl_xor(v, 8, 64));
      const float mn = fmaxf(m[j], v);
      corr[j] = __expf(m[j] - mn);
      m[j] = mn;
    }
    float rs[4] = {0.f, 0.f, 0.f, 0.f};
#pragma unroll
    for (int tj = 0; tj < 4; ++tj)
#pragma unroll
      for (int j = 0; j < 4; ++j) {
        const float p = __expf(s[tj][j] - m[j]);
        rs[j] += p;
        const int prow = roff + j;
        *(unsigned short*)((char*)Ps[w] + prow * 128 + (((tj * 16 + lr) * 2) ^ ((prow & 7) << 4))) = f2b(p);
      }
#pragma unroll
    for (int j = 0; j < 4; ++j) {
      float v = rs[j];
      v += __shfl_xor(v, 1, 64);
      v += __shfl_xor(v, 2, 64);
      v += __shfl_xor(v, 4, 64);
      v += __shfl_xor(v, 8, 64);
      lsum[j] = lsum[j] * corr[j] + v;
    }
#pragma unroll
    for (int nj = 0; nj < 8; ++nj)
#pragma unroll
      for (int j = 0; j < 4; ++j) o[nj][j] *= corr[j];

    // O += P V
    __builtin_amdgcn_s_setprio(1);
#pragma unroll
    for (int ks = 0; ks < 2; ++ks) {
      bf16x8 pf = *(const bf16x8*)((const char*)Ps[w] + lr * 128 + ((ks * 64 + g16) ^ sw));
#pragma unroll
      for (int nj = 0; nj < 8; ++nj) {
        bf16x8 vf = *(const bf16x8*)(VsB + (nj * 16 + lr) * 128 + ((ks * 64 + g16) ^ sw));
        o[nj] = __builtin_amdgcn_mfma_f32_16x16x32_bf16(pf, vf, o[nj], 0, 0, 0);
      }
    }
    __builtin_amdgcn_s_setprio(0);
    __syncthreads();
  }

  float inv[4];
#pragma unroll
  for (int j = 0; j < 4; ++j) inv[j] = 1.0f / lsum[j];
  const int b = bh >> 4, h = bh & 15;
#pragma unroll
  for (int nj = 0; nj < 8; ++nj)
#pragma unroll
    for (int j = 0; j < 4; ++j) {
      const int q = q0 + roff + j;
      const int d = nj * 16 + lr;
      O[(long)(b * T + q) * 2048 + h * 128 + d] = f2b(o[nj][j] * inv[j]);
    }
}

// ---------------- launch ----------------
extern "C" void kernel_launch(void* const* d_in, const int* in_sizes, int n_in,
                              void* d_out, int out_size, void* d_ws, size_t ws_size,
                              hipStream_t stream)
{
  const int B = 2, T = 2048, C = 2048;
  const int M = B * T;        // 4096
  const int N1 = 3 * C;       // 6144
  const float* x    = (const float*)d_in[0];
  const float* Wqkv = (const float*)d_in[1];
  const float* bqkv = (const float*)d_in[2];
  const float* Wout = (const float*)d_in[3];
  const float* bout = (const float*)d_in[4];
  float* out = (float*)d_out;

  char* p = (char*)d_ws;
  unsigned short* xb    = (unsigned short*)p; p += (size_t)M * C * 2;    // 16 MB
  unsigned short* wqkvb = (unsigned short*)p; p += (size_t)N1 * C * 2;   // 24 MB
  unsigned short* woutb = (unsigned short*)p; p += (size_t)C * C * 2;    // 8 MB
  unsigned short* qkv   = (unsigned short*)p; p += (size_t)M * N1 * 2;   // 48 MB
  unsigned short* Qr    = (unsigned short*)p; p += (size_t)M * C * 2;    // 16 MB
  unsigned short* Kr    = (unsigned short*)p; p += (size_t)M * C * 2;    // 16 MB
  unsigned short* Vt    = (unsigned short*)p; p += (size_t)M * C * 2;    // 16 MB
  unsigned short* Ob    = xb;  // xb dead after QKV GEMM — reuse for attention output

  cast_kernel<<<M * C / 1024, 256, 0, stream>>>(x, xb, M * C);
  cast_kernel<<<N1 * C / 1024, 256, 0, stream>>>(Wqkv, wqkvb, N1 * C);
  cast_kernel<<<C * C / 1024, 256, 0, stream>>>(Wout, woutb, C * C);

  gemm_bt<0><<<dim3(N1 / 128, M / 128), 256, 0, stream>>>(xb, wqkvb, bqkv, qkv, M, N1, C);

  rope_kernel<<<(32 * T * 64) / 256, 256, 0, stream>>>(qkv, Qr, Kr);
  vtrans_kernel<<<dim3(T / 64, 32), 256, 0, stream>>>(qkv, Vt);

  attn_fwd<<<dim3(32, T / 64), 256, 0, stream>>>(Qr, Kr, Vt, Ob, T);

  gemm_bt<1><<<dim3(C / 128, M / 128), 256, 0, stream>>>(Ob, woutb, bout, out, M, C, C);
}